// Round 10
// baseline (1933.395 us; speedup 1.0000x reference)
//
#include <hip/hip_runtime.h>

// Persistent LSTM autoencoder V2.
// - unique h buffer per step (129 x 512KB, tile-packed [g][512][8]) ->
//   consumer uses PLAIN 16B loads (no stale-line hazard: address never seen
//   before by the consumer's caches within a kernel)
// - producer h stores: agent-scope 8B write-through, fully packed lines
// - per-wave relaxed flags + vmcnt drain (R7-validated protocol)
// - B weights staged to LDS ONCE per phase; c in registers across 128 steps
// - dec reuses enc's buffers after the kernel boundary; z_final gathers
//   directly from step buffers (Hall eliminated)

#define Bsz 512
#define Tsz 128
#define Esz 256
#define Hsz 512
#define Zsz 256
#define NG  2048                 // 4*Hsz gate columns, interleaved n = 4*j + gate
#define BUFE (64 * 512 * 8)      // f16 elements per h step-buffer (512 KB)

typedef _Float16 f16;
typedef unsigned long long ull;
typedef __attribute__((ext_vector_type(8))) _Float16 f16x8;
typedef __attribute__((ext_vector_type(4))) float f32x4;
typedef __attribute__((ext_vector_type(4))) int i32x4;

__device__ __forceinline__ float sigm(float x) { return 1.0f / (1.0f + __expf(-x)); }
__device__ __forceinline__ float tanh_f(float x) { return __builtin_fmaf(2.f, sigm(2.f * x), -1.f); }
// 8-f16-granule swizzle within 64-col tiles (bits 3..5 ^= r&7) — involution
__device__ __forceinline__ int swz(int kd, int r) {
    return (kd & ~56) | ((((kd >> 3) & 7) ^ (r & 7)) << 3);
}
__device__ __forceinline__ void gld16(const void* g, void* l) {
    __builtin_amdgcn_global_load_lds(
        (const __attribute__((address_space(1))) unsigned*)g,
        (__attribute__((address_space(3))) unsigned*)l, 16, 0, 0);
}
__device__ __forceinline__ void stA(void* p, ull v) {
    __hip_atomic_store((ull*)p, v, __ATOMIC_RELAXED, __HIP_MEMORY_SCOPE_AGENT);
}
__device__ __forceinline__ f16x8 asfrag(i32x4 a) {
    union { i32x4 u; f16x8 v; } x; x.u = a; return x.v;
}

// ---------------------------------------------------------------------------
// prep: buf[0]=0.1; x tile-packed fp16; weights fp16 gate-interleaved
// (swizzled for LDS paths, dhh plain for dec step-0 reg path); biases; flags=0.
// ---------------------------------------------------------------------------
__global__ __launch_bounds__(256) void prep_kernel(
    const float* __restrict__ x,
    const float* __restrict__ enc_W_ih, const float* __restrict__ enc_W_hh,
    const float* __restrict__ enc_b_ih, const float* __restrict__ enc_b_hh,
    const float* __restrict__ dec_W_ih, const float* __restrict__ dec_W_hh,
    const float* __restrict__ dec_b_ih, const float* __restrict__ dec_b_hh,
    const float* __restrict__ z_W,
    f16* __restrict__ xe,    f16* __restrict__ eih_s, f16* __restrict__ ehh_s,
    f16* __restrict__ dhh_p, f16* __restrict__ wsm_s, f16* __restrict__ zw_s,
    float* __restrict__ encB, float* __restrict__ decB, float* __restrict__ decB0,
    f16* __restrict__ hb, unsigned* __restrict__ flags)
{
    const int tid = blockIdx.x * 256 + threadIdx.x;   // 512 blocks
    const int NT  = 512 * 256;

    for (int i = tid; i < 32768; i += NT) flags[i] = 0;
    for (int i = tid; i < BUFE; i += NT) hb[i] = (f16)0.1f;   // h_0

    // xe[((t*32 + g)*512 + b)*8 + e] = x[b][t][g*8 + e]
    for (int i = tid; i < Bsz * Tsz * Esz; i += NT) {
        const int e = i & 7, b = (i >> 3) & 511, g = (i >> 12) & 31, t = i >> 17;
        xe[i] = (f16)x[((size_t)b * Tsz + t) * Esz + g * 8 + e];
    }
    // enc W_ih: [NG][E], swizzled
    for (int i = tid; i < NG * Esz; i += NT) {
        const int n = i >> 8, kd = i & 255;
        const int sr = (n & 3) * Hsz + (n >> 2);
        eih_s[i] = (f16)enc_W_ih[sr * Esz + swz(kd, n)];
    }
    // [NG][H] family
    for (int i = tid; i < NG * Hsz; i += NT) {
        const int n = i >> 9, kd = i & 511;
        const int sr = (n & 3) * Hsz + (n >> 2);
        const int ks = swz(kd, n);
        ehh_s[i] = (f16)enc_W_hh[sr * Hsz + ks];
        wsm_s[i] = (f16)(dec_W_ih[sr * Hsz + ks] + dec_W_hh[sr * Hsz + ks]);
        dhh_p[i] = (f16)dec_W_hh[sr * Hsz + kd];          // plain layout
    }
    // z_W: [Z][H], swizzled
    for (int i = tid; i < Zsz * Hsz; i += NT) {
        const int n = i >> 9, kd = i & 511;
        zw_s[i] = (f16)z_W[n * Hsz + swz(kd, n)];
    }

    const int wave = tid >> 6, lane = tid & 63;   // 2048 waves exactly
    if (wave < NG) {
        const int sr = (wave & 3) * Hsz + (wave >> 2);
        float s = 0.f;
        for (int k = lane; k < Hsz; k += 64) s += dec_W_ih[sr * Hsz + k];
        for (int off = 32; off; off >>= 1) s += __shfl_down(s, off);
        if (lane == 0) {
            encB[wave] = enc_b_ih[sr] + enc_b_hh[sr];
            const float bi = dec_b_ih[sr] + dec_b_hh[sr];
            decB[wave]  = bi;
            decB0[wave] = bi + 0.1f * s;
        }
    }
}

// ---------------------------------------------------------------------------
// Persistent phase. 256 blocks (1/CU); group bx=bid&7 owns rows [bx*64,+64);
// ny=bid>>3 owns gate cols [ny*64,+64). No block barriers in the step loop.
// enc: rd buf[t], wr buf[t+1].  dec: rd (t? buf[t-1] : buf[128]), wr buf[t].
// ---------------------------------------------------------------------------
template <bool ENC>
__global__ __launch_bounds__(256, 1) void persist_kernel(
    const f16* __restrict__ xe, const f16* __restrict__ WihS,
    const f16* __restrict__ BhS, const f16* __restrict__ DhhP,
    const float* __restrict__ biasA, const float* __restrict__ biasB,
    f16* __restrict__ hb, float* __restrict__ cbuf,
    unsigned* __restrict__ flags)
{
    __shared__ __align__(16) f16 Bh[8 * 4096];
    __shared__ __align__(16) f16 Wih[ENC ? 4 * 4096 : 8];
    __shared__ __align__(16) float xch[4][4 * 272];
    __shared__ __align__(16) f16 hx[4][256];

    const int tid = threadIdx.x, bid = blockIdx.x;
    const int bx = bid & 7, ny = bid >> 3;
    const int b0 = bx * 64, n0 = ny * 64;
    const int lane = tid & 63, w = tid >> 6;
    const int lr = lane & 15, lkb = lane >> 4;
    const int wm = (w & 1) * 32, wn = (w >> 1) * 32;
    const int rl = lane >> 3, kc = (lane & 7) * 8;

    // ---- stage read-only B tiles into LDS (once per phase) ----
#pragma unroll
    for (int kt = 0; kt < 8; ++kt)
#pragma unroll
        for (int s2 = 0; s2 < 2; ++s2) {
            const int g = w + s2 * 4, row = g * 8 + rl;
            gld16(BhS + (size_t)(n0 + row) * Hsz + kt * 64 + kc, &Bh[kt * 4096 + g * 512]);
        }
    if (ENC) {
#pragma unroll
        for (int kt = 0; kt < 4; ++kt)
#pragma unroll
            for (int s2 = 0; s2 < 2; ++s2) {
                const int g = w + s2 * 4, row = g * 8 + rl;
                gld16(WihS + (size_t)(n0 + row) * Esz + kt * 64 + kc, &Wih[kt * 4096 + g * 512]);
            }
    }

    float bvA[2], bvB[2];
#pragma unroll
    for (int j = 0; j < 2; ++j) {
        bvA[j] = biasA[n0 + wn + j * 16 + lr];
        bvB[j] = ENC ? 0.f : biasB[n0 + wn + j * 16 + lr];
    }
    // c: thread-private registers across all steps (flat handoff slot)
    const size_t cbase = (((size_t)ny * 8 + bx) * 256 + tid) * 4;
    float cc[4];
    if (ENC) { cc[0] = cc[1] = cc[2] = cc[3] = 0.1f; }
    else {
        const float4 cv = *(const float4*)&cbuf[cbase];
        cc[0] = cv.x; cc[1] = cv.y; cc[2] = cv.z; cc[3] = cv.w;
    }

    asm volatile("s_waitcnt vmcnt(0)" ::: "memory");
    __syncthreads();   // B tiles visible; last block barrier of the kernel

    unsigned* gf   = flags + bx * (128 * 16);
    unsigned* self = gf + (ny * 4 + w) * 16;
    // lane polls ONE producer-wave flag (the 64 covering our 32 A-rows)
    const unsigned* myf = gf + (((lane >> 1) * 4 + (w & 1) + ((lane & 1) << 1)) * 16);

    float* xc  = &xch[w][0];
    f16*  hxw = &hx[w][0];

#pragma unroll 1
    for (int t = 0; t < Tsz; ++t) {
        const f16* hsrc = ENC ? (hb + (size_t)t * BUFE)
                              : (t == 0 ? hb + (size_t)128 * BUFE
                                        : hb + (size_t)(t - 1) * BUFE);
        f16* hdst = ENC ? (hb + (size_t)(t + 1) * BUFE) : (hb + (size_t)t * BUFE);

        f32x4 acc[2][2];
#pragma unroll
        for (int j = 0; j < 2; ++j) {
            const float bv = (!ENC && t == 0) ? bvB[j] : bvA[j];
            acc[0][j] = (f32x4){bv, bv, bv, bv};
            acc[1][j] = acc[0][j];
        }

        // ---- enc: x A-frags + x-part MFMA BEFORE the wait ----
        if (ENC) {
            i32x4 ax[2][8];
#pragma unroll
            for (int i = 0; i < 2; ++i)
#pragma unroll
                for (int s = 0; s < 8; ++s)
                    ax[i][s] = *(const i32x4*)(xe +
                        (((size_t)(t * 32 + s * 4 + lkb)) * 512 + b0 + wm + i * 16 + lr) * 8);
#pragma unroll
            for (int s = 0; s < 8; ++s) {
                f16x8 bq[2];
#pragma unroll
                for (int j = 0; j < 2; ++j) {
                    const int rb = wn + j * 16 + lr;
                    bq[j] = *(const f16x8*)&Wih[(s >> 1) * 4096 + rb * 64 +
                                                ((((s & 1) * 4 + lkb) ^ (rb & 7)) * 8)];
                }
#pragma unroll
                for (int i = 0; i < 2; ++i)
#pragma unroll
                    for (int j = 0; j < 2; ++j)
                        acc[i][j] = __builtin_amdgcn_mfma_f32_16x16x32_f16(
                            asfrag(ax[i][s]), bq[j], acc[i][j], 0, 0, 0);
            }
        }

        // ---- wait for previous step's producers (relaxed agent poll) ----
        if (ENC ? (t > 0) : (t > 0)) {
            const unsigned tgt = (unsigned)t;
            while (__hip_atomic_load(myf, __ATOMIC_RELAXED, __HIP_MEMORY_SCOPE_AGENT) < tgt)
                __builtin_amdgcn_s_sleep(1);
            asm volatile("" ::: "memory");
        }

        // ---- h A-frags: PLAIN 16B loads (fresh addresses; data is at L3) ----
        i32x4 ah[2][16];
#pragma unroll
        for (int i = 0; i < 2; ++i)
#pragma unroll
            for (int s = 0; s < 16; ++s)
                ah[i][s] = *(const i32x4*)(hsrc +
                    (((size_t)(s * 4 + lkb)) * 512 + b0 + wm + i * 16 + lr) * 8);

        // ---- h-part MFMA (LDS B; dec t=0 reads dhh from global) ----
        if (!ENC && t == 0) {
#pragma unroll
            for (int s = 0; s < 16; ++s) {
                f16x8 bq[2];
#pragma unroll
                for (int j = 0; j < 2; ++j)
                    bq[j] = *(const f16x8*)&DhhP[
                        (size_t)(n0 + wn + j * 16 + lr) * Hsz + s * 32 + lkb * 8];
#pragma unroll
                for (int i = 0; i < 2; ++i)
#pragma unroll
                    for (int j = 0; j < 2; ++j)
                        acc[i][j] = __builtin_amdgcn_mfma_f32_16x16x32_f16(
                            asfrag(ah[i][s]), bq[j], acc[i][j], 0, 0, 0);
            }
        } else {
#pragma unroll
            for (int s = 0; s < 16; ++s) {
                f16x8 bq[2];
#pragma unroll
                for (int j = 0; j < 2; ++j) {
                    const int rb = wn + j * 16 + lr;
                    bq[j] = *(const f16x8*)&Bh[(s >> 1) * 4096 + rb * 64 +
                                               ((((s & 1) * 4 + lkb) ^ (rb & 7)) * 8)];
                }
#pragma unroll
                for (int i = 0; i < 2; ++i)
#pragma unroll
                    for (int j = 0; j < 2; ++j)
                        acc[i][j] = __builtin_amdgcn_mfma_f32_16x16x32_f16(
                            asfrag(ah[i][s]), bq[j], acc[i][j], 0, 0, 0);
            }
        }

        // ---- wave-local gate transpose (lgkmcnt only) ----
#pragma unroll
        for (int i = 0; i < 2; ++i)
#pragma unroll
            for (int j = 0; j < 2; ++j)
#pragma unroll
                for (int r = 0; r < 4; ++r)
                    xc[(i * 2 + j) * 272 + lr * 17 + lkb * 4 + r] = acc[i][j][r];
        asm volatile("s_waitcnt lgkmcnt(0)" ::: "memory");

#pragma unroll
        for (int i = 0; i < 2; ++i)
#pragma unroll
            for (int j = 0; j < 2; ++j) {
                const float gi = xc[(i * 2 + j) * 272 + (4 * lkb + 0) * 17 + lr];
                const float gf = xc[(i * 2 + j) * 272 + (4 * lkb + 1) * 17 + lr];
                const float gg = xc[(i * 2 + j) * 272 + (4 * lkb + 2) * 17 + lr];
                const float go = xc[(i * 2 + j) * 272 + (4 * lkb + 3) * 17 + lr];
                const float iv = sigm(gi), fv = sigm(gf);
                const float gv = tanh_f(gg), ov = sigm(go);
                const int q = i * 2 + j;
                const float cn = fv * cc[q] + iv * gv;
                cc[q] = cn;
                hxw[(i * 16 + lr) * 8 + j * 4 + lkb] = (f16)(ov * tanh_f(cn));
            }
        asm volatile("s_waitcnt lgkmcnt(0)" ::: "memory");

        // ---- h store: agent write-through, packed lines (512B per wave) ----
        if (lane < 32) {
            const int g = ny * 2 + (w >> 1);
            const int row = b0 + wm + (lane & 31);
            const ull lo = *(const ull*)&hxw[(lane & 31) * 8];
            const ull hi = *(const ull*)&hxw[(lane & 31) * 8 + 4];
            f16* dp = hdst + ((size_t)g * 512 + row) * 8;
            stA(dp, lo);
            stA(dp + 4, hi);
        }

        // ---- drain own stores, then relaxed flag signal ----
        asm volatile("s_waitcnt vmcnt(0)" ::: "memory");
        if (t < Tsz - 1 && lane == 0)
            __hip_atomic_store(self, (unsigned)(t + 1),
                               __ATOMIC_RELAXED, __HIP_MEMORY_SCOPE_AGENT);
    }

    if (ENC) {
        float4 cv = {cc[0], cc[1], cc[2], cc[3]};
        *(float4*)&cbuf[cbase] = cv;
    }
}

// ---------------------------------------------------------------------------
// z projection from the dec step buffers: out[b][t][:] = tanh(buf[t][.,b] @ zW^T + zb)
// grid (1024, 4): blockIdx.x -> (b = x>>1, t0 = (x&1)*64); 64 t-rows per tile.
// ---------------------------------------------------------------------------
__global__ __launch_bounds__(256, 2) void z_final(
    const f16* __restrict__ hb, const f16* __restrict__ zw,
    const float* __restrict__ zb, float* __restrict__ out)
{
    __shared__ f16 As[2][4096];
    __shared__ f16 Bs[2][4096];

    const int tid = threadIdx.x;
    const int lane = tid & 63, w = tid >> 6;
    const int lr = lane & 15, lkb = lane >> 4;
    const int wm = (w & 1) * 32, wn = (w >> 1) * 32;
    const int b  = blockIdx.x >> 1;
    const int t0 = (blockIdx.x & 1) * 64;
    const int n0 = blockIdx.y * 64;
    const int rl = lane >> 3, kcB = (lane & 7) * 8;
    const int axr = (lane & 7) ^ rl;   // pre-swizzled source chunk for As

    f32x4 acc[2][2];
#pragma unroll
    for (int j = 0; j < 2; ++j) {
        const float bv = zb[n0 + wn + j * 16 + lr];
        acc[0][j] = (f32x4){bv, bv, bv, bv};
        acc[1][j] = acc[0][j];
    }

    auto stage = [&](int buf, int kt) {
#pragma unroll
        for (int s2 = 0; s2 < 2; ++s2) {
            const int g = w + s2 * 4;
            const int trow = t0 + g * 8 + rl;     // this LDS row = time t
            gld16(hb + (size_t)trow * BUFE + ((size_t)(kt * 8 + axr) * 512 + b) * 8,
                  &As[buf][g * 512]);
            const int row = g * 8 + rl;
            gld16(zw + (size_t)(n0 + row) * Hsz + kt * 64 + kcB, &Bs[buf][g * 512]);
        }
    };

    stage(0, 0);
    int cur = 0;
    for (int kt = 0; kt < 8; ++kt) {
        asm volatile("s_waitcnt vmcnt(0)" ::: "memory");
        __syncthreads();
        if (kt + 1 < 8) stage(cur ^ 1, kt + 1);
        f16x8 af[2][2], bf[2][2];
#pragma unroll
        for (int i = 0; i < 2; ++i) {
            const int ra = wm + i * 16 + lr;
            const int rb = wn + i * 16 + lr;
#pragma unroll
            for (int ks = 0; ks < 2; ++ks) {
                af[i][ks] = *(const f16x8*)&As[cur][ra * 64 + (((ks * 4 + lkb) ^ (ra & 7)) * 8)];
                bf[i][ks] = *(const f16x8*)&Bs[cur][rb * 64 + (((ks * 4 + lkb) ^ (rb & 7)) * 8)];
            }
        }
#pragma unroll
        for (int ks = 0; ks < 2; ++ks)
#pragma unroll
            for (int i = 0; i < 2; ++i)
#pragma unroll
                for (int j = 0; j < 2; ++j)
                    acc[i][j] = __builtin_amdgcn_mfma_f32_16x16x32_f16(
                        af[i][ks], bf[j][ks], acc[i][j], 0, 0, 0);
        cur ^= 1;
    }
#pragma unroll
    for (int i = 0; i < 2; ++i)
#pragma unroll
        for (int j = 0; j < 2; ++j)
#pragma unroll
            for (int r = 0; r < 4; ++r) {
                const int t = t0 + wm + i * 16 + lkb * 4 + r;
                const int col = n0 + wn + j * 16 + lr;
                out[((size_t)b * Tsz + t) * Zsz + col] = tanh_f(acc[i][j][r]);
            }
}

// ---------------------------------------------------------------------------
extern "C" void kernel_launch(void* const* d_in, const int* in_sizes, int n_in,
                              void* d_out, int out_size, void* d_ws, size_t ws_size,
                              hipStream_t stream) {
    (void)in_sizes; (void)n_in; (void)out_size; (void)ws_size;
    const float* x        = (const float*)d_in[0];
    const float* enc_W_ih = (const float*)d_in[1];
    const float* enc_W_hh = (const float*)d_in[2];
    const float* enc_b_ih = (const float*)d_in[3];
    const float* enc_b_hh = (const float*)d_in[4];
    const float* dec_W_ih = (const float*)d_in[5];
    const float* dec_W_hh = (const float*)d_in[6];
    const float* dec_b_ih = (const float*)d_in[7];
    const float* dec_b_hh = (const float*)d_in[8];
    const float* z_W      = (const float*)d_in[9];
    const float* z_b      = (const float*)d_in[10];
    float* out = (float*)d_out;

    unsigned* flags = (unsigned*)d_ws;   // [0..16383] enc, [16384..32767] dec
    float* fp    = (float*)(flags + 32768);
    float* encB  = fp;  fp += NG;
    float* decB  = fp;  fp += NG;
    float* decB0 = fp;  fp += NG;
    float* cbuf  = fp;  fp += 256 * 256 * 4;
    f16* hp    = (f16*)fp;
    f16* xe    = hp;  hp += (size_t)Bsz * Tsz * Esz;
    f16* eih_s = hp;  hp += (size_t)NG * Esz;
    f16* ehh_s = hp;  hp += (size_t)NG * Hsz;
    f16* dhh_p = hp;  hp += (size_t)NG * Hsz;
    f16* wsm_s = hp;  hp += (size_t)NG * Hsz;
    f16* zw_s  = hp;  hp += (size_t)Zsz * Hsz;
    f16* hb    = hp;  hp += (size_t)129 * BUFE;   // 129 step buffers

    prep_kernel<<<512, 256, 0, stream>>>(
        x, enc_W_ih, enc_W_hh, enc_b_ih, enc_b_hh,
        dec_W_ih, dec_W_hh, dec_b_ih, dec_b_hh, z_W,
        xe, eih_s, ehh_s, dhh_p, wsm_s, zw_s,
        encB, decB, decB0, hb, flags);

    persist_kernel<true><<<256, 256, 0, stream>>>(
        xe, eih_s, ehh_s, nullptr, encB, nullptr,
        hb, cbuf, flags);

    persist_kernel<false><<<256, 256, 0, stream>>>(
        nullptr, nullptr, wsm_s, dhh_p, decB, decB0,
        hb, cbuf, flags + 16384);

    z_final<<<dim3(1024, 4), 256, 0, stream>>>(hb, zw_s, z_b, out);
}

// Round 11
// 1636.532 us; speedup vs baseline: 1.1814x; 1.1814x over previous
//
#include <hip/hip_runtime.h>

// Persistent LSTM autoencoder V3: 8 waves/block (2/SIMD), K-split partials.
// Protocol identical to R10 (proven): fresh h buffer per step, tile-packed
// [g][512][8], agent write-through stores, plain consumer loads, relaxed
// per-block flags. New: K halved across wave pairs -> TLP hides latency.

#define Bsz 512
#define Tsz 128
#define Esz 256
#define Hsz 512
#define Zsz 256
#define NG  2048                 // 4*Hsz gate columns, interleaved n = 4*j + gate
#define BUFE (64 * 512 * 8)      // f16 elements per h step-buffer (512 KB)

typedef _Float16 f16;
typedef unsigned long long ull;
typedef __attribute__((ext_vector_type(8))) _Float16 f16x8;
typedef __attribute__((ext_vector_type(4))) float f32x4;
typedef __attribute__((ext_vector_type(4))) int i32x4;

__device__ __forceinline__ float sigm(float x) { return 1.0f / (1.0f + __expf(-x)); }
__device__ __forceinline__ float tanh_f(float x) { return __builtin_fmaf(2.f, sigm(2.f * x), -1.f); }
// 8-f16-granule swizzle within 64-col tiles (bits 3..5 ^= r&7) — involution
__device__ __forceinline__ int swz(int kd, int r) {
    return (kd & ~56) | ((((kd >> 3) & 7) ^ (r & 7)) << 3);
}
__device__ __forceinline__ void gld16(const void* g, void* l) {
    __builtin_amdgcn_global_load_lds(
        (const __attribute__((address_space(1))) unsigned*)g,
        (__attribute__((address_space(3))) unsigned*)l, 16, 0, 0);
}
__device__ __forceinline__ void stA(void* p, ull v) {
    __hip_atomic_store((ull*)p, v, __ATOMIC_RELAXED, __HIP_MEMORY_SCOPE_AGENT);
}
__device__ __forceinline__ f16x8 asfrag(i32x4 a) {
    union { i32x4 u; f16x8 v; } x; x.u = a; return x.v;
}

// ---------------------------------------------------------------------------
__global__ __launch_bounds__(256) void prep_kernel(
    const float* __restrict__ x,
    const float* __restrict__ enc_W_ih, const float* __restrict__ enc_W_hh,
    const float* __restrict__ enc_b_ih, const float* __restrict__ enc_b_hh,
    const float* __restrict__ dec_W_ih, const float* __restrict__ dec_W_hh,
    const float* __restrict__ dec_b_ih, const float* __restrict__ dec_b_hh,
    const float* __restrict__ z_W,
    f16* __restrict__ xe,    f16* __restrict__ eih_s, f16* __restrict__ ehh_s,
    f16* __restrict__ dhh_p, f16* __restrict__ wsm_s, f16* __restrict__ zw_s,
    float* __restrict__ encB, float* __restrict__ decB, float* __restrict__ decB0,
    f16* __restrict__ hb, unsigned* __restrict__ flags)
{
    const int tid = blockIdx.x * 256 + threadIdx.x;   // 512 blocks
    const int NT  = 512 * 256;

    for (int i = tid; i < 8192; i += NT) flags[i] = 0;
    for (int i = tid; i < BUFE; i += NT) hb[i] = (f16)0.1f;   // h_0

    // xe[((t*32 + g)*512 + b)*8 + e] = x[b][t][g*8 + e]
    for (int i = tid; i < Bsz * Tsz * Esz; i += NT) {
        const int e = i & 7, b = (i >> 3) & 511, g = (i >> 12) & 31, t = i >> 17;
        xe[i] = (f16)x[((size_t)b * Tsz + t) * Esz + g * 8 + e];
    }
    // enc W_ih: [NG][E], swizzled
    for (int i = tid; i < NG * Esz; i += NT) {
        const int n = i >> 8, kd = i & 255;
        const int sr = (n & 3) * Hsz + (n >> 2);
        eih_s[i] = (f16)enc_W_ih[sr * Esz + swz(kd, n)];
    }
    // [NG][H] family
    for (int i = tid; i < NG * Hsz; i += NT) {
        const int n = i >> 9, kd = i & 511;
        const int sr = (n & 3) * Hsz + (n >> 2);
        const int ks = swz(kd, n);
        ehh_s[i] = (f16)enc_W_hh[sr * Hsz + ks];
        wsm_s[i] = (f16)(dec_W_ih[sr * Hsz + ks] + dec_W_hh[sr * Hsz + ks]);
        dhh_p[i] = (f16)dec_W_hh[sr * Hsz + kd];          // plain layout
    }
    // z_W: [Z][H], swizzled
    for (int i = tid; i < Zsz * Hsz; i += NT) {
        const int n = i >> 9, kd = i & 511;
        zw_s[i] = (f16)z_W[n * Hsz + swz(kd, n)];
    }

    const int wave = tid >> 6, lane = tid & 63;   // 2048 waves exactly
    if (wave < NG) {
        const int sr = (wave & 3) * Hsz + (wave >> 2);
        float s = 0.f;
        for (int k = lane; k < Hsz; k += 64) s += dec_W_ih[sr * Hsz + k];
        for (int off = 32; off; off >>= 1) s += __shfl_down(s, off);
        if (lane == 0) {
            encB[wave] = enc_b_ih[sr] + enc_b_hh[sr];
            const float bi = dec_b_ih[sr] + dec_b_hh[sr];
            decB[wave]  = bi;
            decB0[wave] = bi + 0.1f * s;
        }
    }
}

// ---------------------------------------------------------------------------
// Persistent phase. 256 blocks x 512 thr (8 waves, 2/SIMD).
// Wave w: w2 = w&3 gives (wm,wn) 32x32 quadrant; p = w>>2 gives K-half.
// Partials meet in LDS X[p]; elementwise threads sum and apply LSTM.
// ---------------------------------------------------------------------------
template <bool ENC>
__global__ __launch_bounds__(512, 1) void persist_kernel(
    const f16* __restrict__ xe, const f16* __restrict__ WihS,
    const f16* __restrict__ BhS, const f16* __restrict__ DhhP,
    const float* __restrict__ biasA, const float* __restrict__ biasB,
    f16* __restrict__ hb, float* __restrict__ cbuf,
    unsigned* __restrict__ flags)
{
    __shared__ __align__(16) f16 Bh[8 * 4096];
    __shared__ __align__(16) f16 Wih[ENC ? 4 * 4096 : 8];
    __shared__ __align__(16) float X[2][64][68];    // [p][n_local][row, pad->16B]
    __shared__ __align__(16) unsigned hx32[64][8];  // packed h (2 f16 per u32)
    __shared__ unsigned cnt;

    const int tid = threadIdx.x, bid = blockIdx.x;
    const int bx = bid & 7, ny = bid >> 3;
    const int b0 = bx * 64, n0 = ny * 64;
    const int lane = tid & 63, w = tid >> 6;
    const int w2 = w & 3, p = w >> 2;
    const int lr = lane & 15, lkb = lane >> 4;
    const int wm = (w2 & 1) * 32, wn = (w2 >> 1) * 32;
    const int rl = lane >> 3, kc = (lane & 7) * 8;

    // ---- stage read-only B tiles into LDS (once per phase) ----
#pragma unroll
    for (int kt = 0; kt < 8; ++kt)
        gld16(BhS + (size_t)(n0 + w * 8 + rl) * Hsz + kt * 64 + kc, &Bh[kt * 4096 + w * 512]);
    if (ENC) {
#pragma unroll
        for (int kt = 0; kt < 4; ++kt)
            gld16(WihS + (size_t)(n0 + w * 8 + rl) * Esz + kt * 64 + kc, &Wih[kt * 4096 + w * 512]);
    }
    if (tid == 0) cnt = 0;

    float bvA[2], bvB[2];
#pragma unroll
    for (int j = 0; j < 2; ++j) {
        bvA[j] = biasA[n0 + wn + j * 16 + lr];
        bvB[j] = ENC ? 0.f : biasB[n0 + wn + j * 16 + lr];
    }
    // c: 2 values per thread, fixed (row_e, col-pair) mapping both phases
    const size_t cbase = ((size_t)(ny * 8 + bx) * 512 + tid) * 2;
    float cc0, cc1;
    if (ENC) { cc0 = cc1 = 0.1f; }
    else { cc0 = cbuf[cbase]; cc1 = cbuf[cbase + 1]; }

    asm volatile("s_waitcnt vmcnt(0)" ::: "memory");
    __syncthreads();   // B tiles + cnt visible

    unsigned* gf   = flags + bx * 512;           // 32 blocks x 16 u32
    unsigned* self = gf + ny * 16;
    const unsigned* myf = gf + (p * 16 + lane) * 16;   // lanes<16 poll my K-half's producers

    const int row_e = tid >> 3;   // elementwise row 0..63
    const int j2    = tid & 7;    // col-pair: cols 2*j2, 2*j2+1 (local H-cols)

#pragma unroll 1
    for (int t = 0; t < Tsz; ++t) {
        const f16* hsrc = ENC ? (hb + (size_t)t * BUFE)
                              : (t == 0 ? hb + (size_t)128 * BUFE
                                        : hb + (size_t)(t - 1) * BUFE);
        f16* hdst = ENC ? (hb + (size_t)(t + 1) * BUFE) : (hb + (size_t)t * BUFE);

        f32x4 acc[2][2];
#pragma unroll
        for (int j = 0; j < 2; ++j) {
            const float bv = (p != 0) ? 0.f : ((!ENC && t == 0) ? bvB[j] : bvA[j]);
            acc[0][j] = (f32x4){bv, bv, bv, bv};
            acc[1][j] = acc[0][j];
        }

        // ---- enc: all x-part on p0, BEFORE its poll (overlap with waiting) ----
        if (ENC && p == 0) {
            i32x4 ax[2][8];
#pragma unroll
            for (int i = 0; i < 2; ++i)
#pragma unroll
                for (int s = 0; s < 8; ++s)
                    ax[i][s] = *(const i32x4*)(xe +
                        (((size_t)(t * 32 + s * 4 + lkb)) * 512 + b0 + wm + i * 16 + lr) * 8);
#pragma unroll
            for (int s = 0; s < 8; ++s) {
                f16x8 bq[2];
#pragma unroll
                for (int j = 0; j < 2; ++j) {
                    const int rb = wn + j * 16 + lr;
                    bq[j] = *(const f16x8*)&Wih[(s >> 1) * 4096 + rb * 64 +
                                                ((((s & 1) * 4 + lkb) ^ (rb & 7)) * 8)];
                }
#pragma unroll
                for (int i = 0; i < 2; ++i)
#pragma unroll
                    for (int j = 0; j < 2; ++j)
                        acc[i][j] = __builtin_amdgcn_mfma_f32_16x16x32_f16(
                            asfrag(ax[i][s]), bq[j], acc[i][j], 0, 0, 0);
            }
        }

        // ---- wait for my K-half's producer blocks (relaxed agent poll) ----
        if (t > 0 && lane < 16) {
            const unsigned tgt = (unsigned)t;
            while (__hip_atomic_load(myf, __ATOMIC_RELAXED, __HIP_MEMORY_SCOPE_AGENT) < tgt)
                __builtin_amdgcn_s_sleep(1);
        }
        asm volatile("" ::: "memory");   // keep h loads below the poll

        // ---- h A-frags for my 8 slices: plain 16B loads (fresh addresses) ----
        i32x4 ah[2][8];
#pragma unroll
        for (int i = 0; i < 2; ++i)
#pragma unroll
            for (int u = 0; u < 8; ++u) {
                const int s = p * 8 + u;
                ah[i][u] = *(const i32x4*)(hsrc +
                    (((size_t)(s * 4 + lkb)) * 512 + b0 + wm + i * 16 + lr) * 8);
            }

        // ---- h-part MFMA (LDS B; dec t=0 reads dhh from global) ----
        if (!ENC && t == 0) {
#pragma unroll
            for (int u = 0; u < 8; ++u) {
                const int s = p * 8 + u;
                f16x8 bq[2];
#pragma unroll
                for (int j = 0; j < 2; ++j)
                    bq[j] = *(const f16x8*)&DhhP[
                        (size_t)(n0 + wn + j * 16 + lr) * Hsz + s * 32 + lkb * 8];
#pragma unroll
                for (int i = 0; i < 2; ++i)
#pragma unroll
                    for (int j = 0; j < 2; ++j)
                        acc[i][j] = __builtin_amdgcn_mfma_f32_16x16x32_f16(
                            asfrag(ah[i][u]), bq[j], acc[i][j], 0, 0, 0);
            }
        } else {
#pragma unroll
            for (int u = 0; u < 8; ++u) {
                const int s = p * 8 + u;
                const int kt = s >> 1;
                f16x8 bq[2];
#pragma unroll
                for (int j = 0; j < 2; ++j) {
                    const int rb = wn + j * 16 + lr;
                    bq[j] = *(const f16x8*)&Bh[kt * 4096 + rb * 64 +
                                               ((((s & 1) * 4 + lkb) ^ (rb & 7)) * 8)];
                }
#pragma unroll
                for (int i = 0; i < 2; ++i)
#pragma unroll
                    for (int j = 0; j < 2; ++j)
                        acc[i][j] = __builtin_amdgcn_mfma_f32_16x16x32_f16(
                            asfrag(ah[i][u]), bq[j], acc[i][j], 0, 0, 0);
            }
        }

        // ---- write K-half partials ----
#pragma unroll
        for (int i = 0; i < 2; ++i)
#pragma unroll
            for (int j = 0; j < 2; ++j)
                *(f32x4*)&X[p][wn + j * 16 + lr][wm + i * 16 + lkb * 4] = acc[i][j];
        __syncthreads();   // bar1: partials visible

        // ---- elementwise: sum partials, LSTM, pack h pair ----
        unsigned hpk;
        {
            f16 hh[2];
#pragma unroll
            for (int q = 0; q < 2; ++q) {
                const int nb = 8 * j2 + 4 * q;
                const float gi = X[0][nb + 0][row_e] + X[1][nb + 0][row_e];
                const float gF = X[0][nb + 1][row_e] + X[1][nb + 1][row_e];
                const float gg = X[0][nb + 2][row_e] + X[1][nb + 2][row_e];
                const float go = X[0][nb + 3][row_e] + X[1][nb + 3][row_e];
                const float iv = sigm(gi), fv = sigm(gF);
                const float gv = tanh_f(gg), ov = sigm(go);
                float& c = q ? cc1 : cc0;
                const float cn = fv * c + iv * gv;
                c = cn;
                hh[q] = (f16)(ov * tanh_f(cn));
            }
            __builtin_memcpy(&hpk, hh, 4);
        }
        hx32[row_e][j2] = hpk;
        __syncthreads();   // bar2: hx complete

        // ---- h store (waves 0,1): packed 16B lines, agent write-through ----
        if (tid < 128) {
            const int row2 = tid >> 1, half = tid & 1;
            const int g = ny * 2 + half;
            const ull lo = *(const ull*)&hx32[row2][half * 4];
            const ull hi = *(const ull*)&hx32[row2][half * 4 + 2];
            f16* dp = hdst + ((size_t)g * 512 + b0 + row2) * 8;
            stA(dp, lo);
            stA(dp + 4, hi);
            asm volatile("s_waitcnt vmcnt(0)" ::: "memory");
            if (t < Tsz - 1 && (tid & 63) == 0) {
                const unsigned old = __hip_atomic_fetch_add(&cnt, 1u,
                    __ATOMIC_RELAXED, __HIP_MEMORY_SCOPE_WORKGROUP);
                if (old == 2u * (unsigned)t + 1u)
                    __hip_atomic_store(self, (unsigned)(t + 1),
                                       __ATOMIC_RELAXED, __HIP_MEMORY_SCOPE_AGENT);
            }
        }
    }

    if (ENC) {
        cbuf[cbase]     = cc0;
        cbuf[cbase + 1] = cc1;
    }
}

// ---------------------------------------------------------------------------
// z projection from the dec step buffers (R10-proven path).
// grid (1024, 4): blockIdx.x -> (b = x>>1, t0 = (x&1)*64).
// ---------------------------------------------------------------------------
__global__ __launch_bounds__(256, 2) void z_final(
    const f16* __restrict__ hb, const f16* __restrict__ zw,
    const float* __restrict__ zb, float* __restrict__ out)
{
    __shared__ f16 As[2][4096];
    __shared__ f16 Bs[2][4096];

    const int tid = threadIdx.x;
    const int lane = tid & 63, w = tid >> 6;
    const int lr = lane & 15, lkb = lane >> 4;
    const int wm = (w & 1) * 32, wn = (w >> 1) * 32;
    const int b  = blockIdx.x >> 1;
    const int t0 = (blockIdx.x & 1) * 64;
    const int n0 = blockIdx.y * 64;
    const int rl = lane >> 3, kcB = (lane & 7) * 8;
    const int axr = (lane & 7) ^ rl;   // pre-swizzled source chunk for As

    f32x4 acc[2][2];
#pragma unroll
    for (int j = 0; j < 2; ++j) {
        const float bv = zb[n0 + wn + j * 16 + lr];
        acc[0][j] = (f32x4){bv, bv, bv, bv};
        acc[1][j] = acc[0][j];
    }

    auto stage = [&](int buf, int kt) {
#pragma unroll
        for (int s2 = 0; s2 < 2; ++s2) {
            const int g = w + s2 * 4;
            const int trow = t0 + g * 8 + rl;     // this LDS row = time t
            gld16(hb + (size_t)trow * BUFE + ((size_t)(kt * 8 + axr) * 512 + b) * 8,
                  &As[buf][g * 512]);
            const int row = g * 8 + rl;
            gld16(zw + (size_t)(n0 + row) * Hsz + kt * 64 + kcB, &Bs[buf][g * 512]);
        }
    };

    stage(0, 0);
    int cur = 0;
    for (int kt = 0; kt < 8; ++kt) {
        asm volatile("s_waitcnt vmcnt(0)" ::: "memory");
        __syncthreads();
        if (kt + 1 < 8) stage(cur ^ 1, kt + 1);
        f16x8 af[2][2], bf[2][2];
#pragma unroll
        for (int i = 0; i < 2; ++i) {
            const int ra = wm + i * 16 + lr;
            const int rb = wn + i * 16 + lr;
#pragma unroll
            for (int ks = 0; ks < 2; ++ks) {
                af[i][ks] = *(const f16x8*)&As[cur][ra * 64 + (((ks * 4 + lkb) ^ (ra & 7)) * 8)];
                bf[i][ks] = *(const f16x8*)&Bs[cur][rb * 64 + (((ks * 4 + lkb) ^ (rb & 7)) * 8)];
            }
        }
#pragma unroll
        for (int ks = 0; ks < 2; ++ks)
#pragma unroll
            for (int i = 0; i < 2; ++i)
#pragma unroll
                for (int j = 0; j < 2; ++j)
                    acc[i][j] = __builtin_amdgcn_mfma_f32_16x16x32_f16(
                        af[i][ks], bf[j][ks], acc[i][j], 0, 0, 0);
        cur ^= 1;
    }
#pragma unroll
    for (int i = 0; i < 2; ++i)
#pragma unroll
        for (int j = 0; j < 2; ++j)
#pragma unroll
            for (int r = 0; r < 4; ++r) {
                const int t = t0 + wm + i * 16 + lkb * 4 + r;
                const int col = n0 + wn + j * 16 + lr;
                out[((size_t)b * Tsz + t) * Zsz + col] = tanh_f(acc[i][j][r]);
            }
}

// ---------------------------------------------------------------------------
extern "C" void kernel_launch(void* const* d_in, const int* in_sizes, int n_in,
                              void* d_out, int out_size, void* d_ws, size_t ws_size,
                              hipStream_t stream) {
    (void)in_sizes; (void)n_in; (void)out_size; (void)ws_size;
    const float* x        = (const float*)d_in[0];
    const float* enc_W_ih = (const float*)d_in[1];
    const float* enc_W_hh = (const float*)d_in[2];
    const float* enc_b_ih = (const float*)d_in[3];
    const float* enc_b_hh = (const float*)d_in[4];
    const float* dec_W_ih = (const float*)d_in[5];
    const float* dec_W_hh = (const float*)d_in[6];
    const float* dec_b_ih = (const float*)d_in[7];
    const float* dec_b_hh = (const float*)d_in[8];
    const float* z_W      = (const float*)d_in[9];
    const float* z_b      = (const float*)d_in[10];
    float* out = (float*)d_out;

    unsigned* flags = (unsigned*)d_ws;   // [0..4095] enc, [4096..8191] dec
    float* fp    = (float*)(flags + 8192);
    float* encB  = fp;  fp += NG;
    float* decB  = fp;  fp += NG;
    float* decB0 = fp;  fp += NG;
    float* cbuf  = fp;  fp += 512 * 512;
    f16* hp    = (f16*)fp;
    f16* xe    = hp;  hp += (size_t)Bsz * Tsz * Esz;
    f16* eih_s = hp;  hp += (size_t)NG * Esz;
    f16* ehh_s = hp;  hp += (size_t)NG * Hsz;
    f16* dhh_p = hp;  hp += (size_t)NG * Hsz;
    f16* wsm_s = hp;  hp += (size_t)NG * Hsz;
    f16* zw_s  = hp;  hp += (size_t)Zsz * Hsz;
    f16* hb    = hp;  hp += (size_t)129 * BUFE;   // 129 step buffers

    prep_kernel<<<512, 256, 0, stream>>>(
        x, enc_W_ih, enc_W_hh, enc_b_ih, enc_b_hh,
        dec_W_ih, dec_W_hh, dec_b_ih, dec_b_hh, z_W,
        xe, eih_s, ehh_s, dhh_p, wsm_s, zw_s,
        encB, decB, decB0, hb, flags);

    persist_kernel<true><<<256, 512, 0, stream>>>(
        xe, eih_s, ehh_s, nullptr, encB, nullptr,
        hb, cbuf, flags);

    persist_kernel<false><<<256, 512, 0, stream>>>(
        nullptr, nullptr, wsm_s, dhh_p, decB, decB0,
        hb, cbuf, flags + 4096);

    z_final<<<dim3(1024, 4), 256, 0, stream>>>(hb, zw_s, z_b, out);
}